// Round 2
// baseline (1107.254 us; speedup 1.0000x reference)
//
#include <hip/hip_runtime.h>

// GATConv (PyG, edge_dim, concat): N=100000, E=1e6, IN=64, H=4, C=32.
// fp32 inputs: x[N,64], edge_index (int32 or int64, auto-detected) [2,E],
// edge_attr[E,16], W[64,128], W_edge[16,128], att_src/dst/edge[4,32], bias[128].
// Output fp32 [N,128].

#define HC 128
#define NEG 0.2f

// order-preserving float<->uint for atomicMax over signed floats
__device__ __forceinline__ unsigned fordk(float f) {
    unsigned u = __float_as_uint(f);
    return (u & 0x80000000u) ? ~u : (u | 0x80000000u);
}
__device__ __forceinline__ float fordi(unsigned k) {
    return __uint_as_float((k & 0x80000000u) ? (k ^ 0x80000000u) : ~k);
}

// edge_index may be int32 (harness-converted) or raw int64. Detect once:
// int64 little-endian with values < 2^31 => odd 32-bit words all zero.
__global__ void k_detect(const int* __restrict__ ei, int* __restrict__ flag) {
    if (threadIdx.x == 0) {
        int any = 0;
        for (int i = 1; i < 64; i += 2) any |= ei[i];
        flag[0] = (any == 0) ? 1 : 0;
    }
}

__device__ __forceinline__ long ld_idx(const int* __restrict__ ei, long i, int m64) {
    return m64 ? (long)(((const long long*)ei)[i]) : (long)ei[i];
}

__global__ void k_zero(uint4* __restrict__ p, long n4) {
    long i = (long)blockIdx.x * blockDim.x + threadIdx.x;
    if (i < n4) p[i] = make_uint4(0u, 0u, 0u, 0u);
}

// q[d*4+h] = sum_c W_edge[d, h*32+c] * att_edge[h, c]  (folds e_proj away)
__global__ void k_q(const float* __restrict__ We, const float* __restrict__ ae,
                    float* __restrict__ q) {
    int t = threadIdx.x;
    if (t >= 64) return;
    int d = t >> 2, h = t & 3;
    float s = 0.f;
    for (int c = 0; c < 32; ++c)
        s += We[d * HC + h * 32 + c] * ae[h * 32 + c];
    q[t] = s;
}

// per node: x_proj, a_src, a_dst
__global__ __launch_bounds__(128) void k_proj(
    const float* __restrict__ x, const float* __restrict__ W,
    const float* __restrict__ as_, const float* __restrict__ ad_,
    float* __restrict__ xp, float* __restrict__ a_src, float* __restrict__ a_dst,
    int N) {
    int n = blockIdx.x;
    if (n >= N) return;
    int t = threadIdx.x;  // output column; h = t>>5
    __shared__ float xs[64];
    if (t < 64) xs[t] = x[(long)n * 64 + t];
    __syncthreads();
    float acc = 0.f;
#pragma unroll
    for (int f = 0; f < 64; ++f) acc += xs[f] * W[f * HC + t];
    xp[(long)n * HC + t] = acc;
    float vs = acc * as_[t];
    float vd = acc * ad_[t];
#pragma unroll
    for (int off = 16; off > 0; off >>= 1) {
        vs += __shfl_down(vs, off, 32);
        vd += __shfl_down(vd, off, 32);
    }
    if ((t & 31) == 0) {
        int h = t >> 5;
        a_src[(long)n * 4 + h] = vs;
        a_dst[(long)n * 4 + h] = vd;
    }
}

// per edge: alpha = leakyrelu(a_src[s]+a_dst[d]+ea.q); store; atomicMax segmax
__global__ __launch_bounds__(256) void k_edgeA(
    const int* __restrict__ ei, const int* __restrict__ flag,
    const float* __restrict__ ea, const float* __restrict__ q,
    const float* __restrict__ a_src, const float* __restrict__ a_dst,
    float* __restrict__ alpha, unsigned* __restrict__ m, int E) {
    int e = blockIdx.x * blockDim.x + threadIdx.x;
    if (e >= E) return;
    int m64 = flag[0];
    long s = ld_idx(ei, e, m64);
    long d = ld_idx(ei, (long)E + e, m64);
    const float4* pe = reinterpret_cast<const float4*>(ea + (long)e * 16);
    float4 e0 = pe[0], e1 = pe[1], e2 = pe[2], e3 = pe[3];
    float ev[16] = {e0.x, e0.y, e0.z, e0.w, e1.x, e1.y, e1.z, e1.w,
                    e2.x, e2.y, e2.z, e2.w, e3.x, e3.y, e3.z, e3.w};
    float4 s4 = *reinterpret_cast<const float4*>(a_src + s * 4);
    float4 d4 = *reinterpret_cast<const float4*>(a_dst + d * 4);
    float sv[4] = {s4.x, s4.y, s4.z, s4.w};
    float dv[4] = {d4.x, d4.y, d4.z, d4.w};
    float ov[4];
#pragma unroll
    for (int h = 0; h < 4; ++h) {
        float aev = 0.f;
#pragma unroll
        for (int dd = 0; dd < 16; ++dd) aev += ev[dd] * q[dd * 4 + h];
        float al = sv[h] + dv[h] + aev;
        al = (al > 0.f) ? al : NEG * al;
        ov[h] = al;
        atomicMax(&m[d * 4 + h], fordk(al));
    }
    *reinterpret_cast<float4*>(alpha + (long)e * 4) =
        make_float4(ov[0], ov[1], ov[2], ov[3]);
}

// per edge: ex = exp(alpha - segmax[dst]) in place; atomicAdd denom
__global__ __launch_bounds__(256) void k_edgeB(
    const int* __restrict__ ei, const int* __restrict__ flag,
    float* alpha_ex, const unsigned* __restrict__ m, float* __restrict__ denom,
    int E) {
    int e = blockIdx.x * blockDim.x + threadIdx.x;
    if (e >= E) return;
    int m64 = flag[0];
    long d = ld_idx(ei, (long)E + e, m64);
    float4 al = *reinterpret_cast<const float4*>(alpha_ex + (long)e * 4);
    const unsigned* mp = m + d * 4;
    float v0 = expf(al.x - fordi(mp[0]));
    float v1 = expf(al.y - fordi(mp[1]));
    float v2 = expf(al.z - fordi(mp[2]));
    float v3 = expf(al.w - fordi(mp[3]));
    *reinterpret_cast<float4*>(alpha_ex + (long)e * 4) = make_float4(v0, v1, v2, v3);
    atomicAdd(&denom[d * 4 + 0], v0);
    atomicAdd(&denom[d * 4 + 1], v1);
    atomicAdd(&denom[d * 4 + 2], v2);
    atomicAdd(&denom[d * 4 + 3], v3);
}

// per edge x 128 channels: acc[dst] += ex * xp[src]  (acc = d_out, pre-zeroed)
__global__ __launch_bounds__(256) void k_scatter(
    const int* __restrict__ ei, const int* __restrict__ flag,
    const float* __restrict__ ex, const float* __restrict__ xp,
    float* __restrict__ acc, int E) {
    int t = threadIdx.x;
    int e = blockIdx.x * 2 + (t >> 7);
    if (e >= E) return;
    int c = t & 127;
    int m64 = flag[0];
    long s = ld_idx(ei, e, m64);
    long d = ld_idx(ei, (long)E + e, m64);
    float w = ex[(long)e * 4 + (c >> 5)];
    float v = xp[s * HC + c] * w;
    atomicAdd(&acc[d * HC + c], v);
}

// out = out/(denom+eps) + bias, in place
__global__ __launch_bounds__(256) void k_final(
    float* __restrict__ out, const float* __restrict__ denom,
    const float* __restrict__ bias, long total) {
    long i = (long)blockIdx.x * blockDim.x + threadIdx.x;
    if (i >= total) return;
    int c = (int)(i & 127);
    long n = i >> 7;
    float dn = denom[n * 4 + (c >> 5)];
    out[i] = out[i] / (dn + 1e-16f) + bias[c];
}

extern "C" void kernel_launch(void* const* d_in, const int* in_sizes, int n_in,
                              void* d_out, int out_size, void* d_ws, size_t ws_size,
                              hipStream_t stream) {
    const float* x    = (const float*)d_in[0];
    const int*   ei   = (const int*)d_in[1];
    const float* ea   = (const float*)d_in[2];
    const float* W    = (const float*)d_in[3];
    const float* We   = (const float*)d_in[4];
    const float* as_  = (const float*)d_in[5];
    const float* ad_  = (const float*)d_in[6];
    const float* ae   = (const float*)d_in[7];
    const float* bias = (const float*)d_in[8];
    float* out = (float*)d_out;

    int N = in_sizes[0] / 64;
    int E = in_sizes[1] / 2;

    char* ws = (char*)d_ws;
    size_t off = 0;
    auto take = [&](size_t bytes) -> char* {
        char* p = ws + off;
        off += (bytes + 511) & ~(size_t)511;
        return p;
    };
    float* xp    = (float*)take((size_t)N * HC * 4);  // 51.2 MB
    float* a_src = (float*)take((size_t)N * 4 * 4);   // 1.6 MB
    float* a_dst = (float*)take((size_t)N * 4 * 4);   // 1.6 MB
    float* alpha = (float*)take((size_t)E * 4 * 4);   // 16 MB (alpha -> ex in place)
    float* qb    = (float*)take(64 * 4);
    int*   flag  = (int*)take(64);
    char* zbase  = ws + off;                          // zeroed region start
    unsigned* m  = (unsigned*)take((size_t)N * 4 * 4);
    float* denom = (float*)take((size_t)N * 4 * 4);
    long z4 = (long)(((ws + off) - zbase) / 16);

    hipLaunchKernelGGL(k_detect, dim3(1), dim3(64), 0, stream, ei, flag);
    hipLaunchKernelGGL(k_zero, dim3((unsigned)((z4 + 255) / 256)), dim3(256), 0,
                       stream, (uint4*)zbase, z4);
    long o4 = (long)out_size / 4;  // out_size fp32 elems -> uint4 count
    hipLaunchKernelGGL(k_zero, dim3((unsigned)((o4 + 255) / 256)), dim3(256), 0,
                       stream, (uint4*)out, o4);
    hipLaunchKernelGGL(k_q, dim3(1), dim3(64), 0, stream, We, ae, qb);
    hipLaunchKernelGGL(k_proj, dim3(N), dim3(128), 0, stream,
                       x, W, as_, ad_, xp, a_src, a_dst, N);
    hipLaunchKernelGGL(k_edgeA, dim3((E + 255) / 256), dim3(256), 0, stream,
                       ei, flag, ea, qb, a_src, a_dst, alpha, m, E);
    hipLaunchKernelGGL(k_edgeB, dim3((E + 255) / 256), dim3(256), 0, stream,
                       ei, flag, alpha, m, denom, E);
    hipLaunchKernelGGL(k_scatter, dim3((E + 1) / 2), dim3(256), 0, stream,
                       ei, flag, alpha, xp, out, E);
    long total = (long)N * HC;
    hipLaunchKernelGGL(k_final, dim3((unsigned)((total + 255) / 256)), dim3(256), 0,
                       stream, out, denom, bias, total);
}

// Round 3
// 459.577 us; speedup vs baseline: 2.4093x; 2.4093x over previous
//
#include <hip/hip_runtime.h>

// GATConv (PyG, edge_dim, concat): N=100000, E=1e6, IN=64, H=4, C=32.
// fp32 inputs: x[N,64], edge_index (int32/int64 auto-detected) [2,E],
// edge_attr[E,16], W[64,128], W_edge[16,128], att_src/dst/edge[4,32], bias[128].
// Output fp32 [N,128].
//
// Round 3: scatter-atomics -> CSR build + per-destination-wave gather with
// online softmax. Eliminates ~140M fp32 atomics (k_edgeA/B/k_scatter/k_final).

#define HC 128
#define NEG 0.2f
#define NEG_INF (-3.0e38f)

// edge_index may be int32 or raw int64 (LE, values < 2^31 => odd words zero).
__global__ void k_detect(const int* __restrict__ ei, int* __restrict__ flag) {
    if (threadIdx.x == 0) {
        int any = 0;
        for (int i = 1; i < 64; i += 2) any |= ei[i];
        flag[0] = (any == 0) ? 1 : 0;
    }
}
__device__ __forceinline__ long ld_idx(const int* __restrict__ ei, long i, int m64) {
    return m64 ? (long)(((const long long*)ei)[i]) : (long)ei[i];
}

__global__ void k_zero(uint4* __restrict__ p, long n4) {
    long i = (long)blockIdx.x * blockDim.x + threadIdx.x;
    if (i < n4) p[i] = make_uint4(0u, 0u, 0u, 0u);
}

// q[d*4+h] = sum_c W_edge[d, h*32+c] * att_edge[h, c]  (folds e_proj away)
__global__ void k_q(const float* __restrict__ We, const float* __restrict__ ae,
                    float* __restrict__ q) {
    int t = threadIdx.x;
    if (t >= 64) return;
    int d = t >> 2, h = t & 3;
    float s = 0.f;
    for (int c = 0; c < 32; ++c) s += We[d * HC + h * 32 + c] * ae[h * 32 + c];
    q[t] = s;
}

// per node: x_proj, a_src, a_dst
__global__ __launch_bounds__(128) void k_proj(
    const float* __restrict__ x, const float* __restrict__ W,
    const float* __restrict__ as_, const float* __restrict__ ad_,
    float* __restrict__ xp, float* __restrict__ a_src, float* __restrict__ a_dst,
    int N) {
    int n = blockIdx.x;
    if (n >= N) return;
    int t = threadIdx.x;  // output column; h = t>>5
    __shared__ float xs[64];
    if (t < 64) xs[t] = x[(long)n * 64 + t];
    __syncthreads();
    float acc = 0.f;
#pragma unroll
    for (int f = 0; f < 64; ++f) acc += xs[f] * W[f * HC + t];
    xp[(long)n * HC + t] = acc;
    float vs = acc * as_[t];
    float vd = acc * ad_[t];
#pragma unroll
    for (int off = 16; off > 0; off >>= 1) {
        vs += __shfl_down(vs, off, 32);
        vd += __shfl_down(vd, off, 32);
    }
    if ((t & 31) == 0) {
        int h = t >> 5;
        a_src[(long)n * 4 + h] = vs;
        a_dst[(long)n * 4 + h] = vd;
    }
}

// histogram of destinations
__global__ __launch_bounds__(256) void k_hist(
    const int* __restrict__ ei, const int* __restrict__ flag,
    int* __restrict__ deg, int E) {
    int e = blockIdx.x * blockDim.x + threadIdx.x;
    if (e >= E) return;
    long d = ld_idx(ei, (long)E + e, flag[0]);
    atomicAdd(&deg[d], 1);
}

// ---- exclusive scan over deg[N] (chunk=1024 per block of 256 threads) ----
__global__ __launch_bounds__(256) void k_scan1(
    const int* __restrict__ deg, int* __restrict__ row, int* __restrict__ bsum,
    int N) {
    __shared__ int s[256];
    int b = blockIdx.x, t = threadIdx.x;
    int base = b * 1024 + t * 4;
    int v[4], sum = 0;
#pragma unroll
    for (int i = 0; i < 4; ++i) {
        int idx = base + i;
        v[i] = (idx < N) ? deg[idx] : 0;
        sum += v[i];
    }
    s[t] = sum;
    __syncthreads();
    for (int off = 1; off < 256; off <<= 1) {
        int x = (t >= off) ? s[t - off] : 0;
        __syncthreads();
        s[t] += x;
        __syncthreads();
    }
    int run = s[t] - sum;  // exclusive prefix for this thread
#pragma unroll
    for (int i = 0; i < 4; ++i) {
        int idx = base + i;
        if (idx < N) row[idx] = run;
        run += v[i];
    }
    if (t == 255) bsum[b] = s[255];
}

__global__ void k_scan2(int* __restrict__ bsum, int nb) {
    if (threadIdx.x == 0) {
        int run = 0;
        for (int i = 0; i < nb; ++i) { int v = bsum[i]; bsum[i] = run; run += v; }
    }
}

__global__ __launch_bounds__(256) void k_scan3(
    int* __restrict__ row, const int* __restrict__ bsum, int* __restrict__ cursor,
    int N, int E) {
    int i = blockIdx.x * blockDim.x + threadIdx.x;
    if (i < N) {
        int r = row[i] + bsum[i >> 10];
        row[i] = r;
        cursor[i] = r;
    }
    if (i == 0) row[N] = E;
}

// place edges into CSR order; precompute val[h] = a_src[src][h] + edge_attr.q
__global__ __launch_bounds__(256) void k_place(
    const int* __restrict__ ei, const int* __restrict__ flag,
    const float* __restrict__ ea, const float* __restrict__ q,
    const float* __restrict__ a_src, int* __restrict__ cursor,
    int* __restrict__ srt_src, float4* __restrict__ srt_val, int E) {
    int e = blockIdx.x * blockDim.x + threadIdx.x;
    if (e >= E) return;
    int m64 = flag[0];
    long s = ld_idx(ei, e, m64);
    long d = ld_idx(ei, (long)E + e, m64);
    const float4* pe = reinterpret_cast<const float4*>(ea + (long)e * 16);
    float4 e0 = pe[0], e1 = pe[1], e2 = pe[2], e3 = pe[3];
    float ev[16] = {e0.x, e0.y, e0.z, e0.w, e1.x, e1.y, e1.z, e1.w,
                    e2.x, e2.y, e2.z, e2.w, e3.x, e3.y, e3.z, e3.w};
    float4 s4 = *reinterpret_cast<const float4*>(a_src + s * 4);
    float sv[4] = {s4.x, s4.y, s4.z, s4.w};
    float ov[4];
#pragma unroll
    for (int h = 0; h < 4; ++h) {
        float aev = 0.f;
#pragma unroll
        for (int dd = 0; dd < 16; ++dd) aev += ev[dd] * q[dd * 4 + h];
        ov[h] = sv[h] + aev;
    }
    int pos = atomicAdd(&cursor[d], 1);
    srt_src[pos] = (int)s;
    srt_val[pos] = make_float4(ov[0], ov[1], ov[2], ov[3]);
}

// one wave (64 lanes) per destination node; 2 nodes per 128-block.
// online softmax over the node's edges; lane owns channels (lane, lane+64).
__global__ __launch_bounds__(128) void k_gather(
    const int* __restrict__ row, const int* __restrict__ srt_src,
    const float4* __restrict__ srt_val, const float* __restrict__ a_dst,
    const float* __restrict__ xp, const float* __restrict__ bias,
    float* __restrict__ out, int N) {
    int wid = threadIdx.x >> 6;
    int lane = threadIdx.x & 63;
    int n = blockIdx.x * 2 + wid;
    if (n >= N) return;
    int beg = row[n], end = row[n + 1];
    float4 ad = *reinterpret_cast<const float4*>(a_dst + (long)n * 4);
    float adv[4] = {ad.x, ad.y, ad.z, ad.w};

    float m[4] = {NEG_INF, NEG_INF, NEG_INF, NEG_INF};
    float l[4] = {0.f, 0.f, 0.f, 0.f};
    float acc0 = 0.f, acc1 = 0.f;  // channels lane, lane+64
    int h0 = lane >> 5, h1 = 2 + (lane >> 5);

    __shared__ float s_ex[2][64][4];
    __shared__ int s_src[2][64];

    for (int cs = beg; cs < end; cs += 64) {
        int cnt = min(64, end - cs);
        float a[4] = {NEG_INF, NEG_INF, NEG_INF, NEG_INF};
        int srcv = 0;
        if (lane < cnt) {
            srcv = srt_src[cs + lane];
            float4 v = srt_val[cs + lane];
            float t0 = v.x + adv[0], t1 = v.y + adv[1];
            float t2 = v.z + adv[2], t3 = v.w + adv[3];
            a[0] = (t0 > 0.f) ? t0 : NEG * t0;
            a[1] = (t1 > 0.f) ? t1 : NEG * t1;
            a[2] = (t2 > 0.f) ? t2 : NEG * t2;
            a[3] = (t3 > 0.f) ? t3 : NEG * t3;
        }
        // wave max per head
        float cm[4] = {a[0], a[1], a[2], a[3]};
#pragma unroll
        for (int off = 32; off > 0; off >>= 1) {
#pragma unroll
            for (int h = 0; h < 4; ++h)
                cm[h] = fmaxf(cm[h], __shfl_xor(cm[h], off, 64));
        }
        float nm[4], ex[4], sume[4];
#pragma unroll
        for (int h = 0; h < 4; ++h) {
            nm[h] = fmaxf(m[h], cm[h]);
            ex[h] = (lane < cnt) ? __expf(a[h] - nm[h]) : 0.f;
            sume[h] = ex[h];
        }
#pragma unroll
        for (int off = 32; off > 0; off >>= 1) {
#pragma unroll
            for (int h = 0; h < 4; ++h) sume[h] += __shfl_xor(sume[h], off, 64);
        }
        float sc[4];
#pragma unroll
        for (int h = 0; h < 4; ++h) {
            sc[h] = __expf(m[h] - nm[h]);
            l[h] = l[h] * sc[h] + sume[h];
            m[h] = nm[h];
        }
        acc0 *= sc[h0];
        acc1 *= sc[h1];
        s_src[wid][lane] = srcv;
#pragma unroll
        for (int h = 0; h < 4; ++h) s_ex[wid][lane][h] = ex[h];
        // single-wave lockstep: LDS writes above precede reads below in
        // program order for all 64 lanes; no barrier needed.
        for (int j = 0; j < cnt; ++j) {
            long s = s_src[wid][j];
            float w0 = s_ex[wid][j][h0];
            float w1 = s_ex[wid][j][h1];
            acc0 += w0 * xp[s * HC + lane];
            acc1 += w1 * xp[s * HC + 64 + lane];
        }
    }
    float d0 = l[h0] + 1e-16f, d1 = l[h1] + 1e-16f;
    out[(long)n * HC + lane] = acc0 / d0 + bias[lane];
    out[(long)n * HC + 64 + lane] = acc1 / d1 + bias[64 + lane];
}

extern "C" void kernel_launch(void* const* d_in, const int* in_sizes, int n_in,
                              void* d_out, int out_size, void* d_ws, size_t ws_size,
                              hipStream_t stream) {
    const float* x    = (const float*)d_in[0];
    const int*   ei   = (const int*)d_in[1];
    const float* ea   = (const float*)d_in[2];
    const float* W    = (const float*)d_in[3];
    const float* We   = (const float*)d_in[4];
    const float* as_  = (const float*)d_in[5];
    const float* ad_  = (const float*)d_in[6];
    const float* ae   = (const float*)d_in[7];
    const float* bias = (const float*)d_in[8];
    float* out = (float*)d_out;

    int N = in_sizes[0] / 64;
    int E = in_sizes[1] / 2;

    char* ws = (char*)d_ws;
    size_t off = 0;
    auto take = [&](size_t bytes) -> char* {
        char* p = ws + off;
        off += (bytes + 511) & ~(size_t)511;
        return p;
    };
    float* xp      = (float*)take((size_t)N * HC * 4);   // 51.2 MB
    float* a_src   = (float*)take((size_t)N * 4 * 4);    // 1.6 MB
    float* a_dst   = (float*)take((size_t)N * 4 * 4);    // 1.6 MB
    float4* srt_val= (float4*)take((size_t)E * 16);      // 16 MB
    int* srt_src   = (int*)take((size_t)E * 4);          // 4 MB
    int* row       = (int*)take((size_t)(N + 1) * 4);
    int* cursor    = (int*)take((size_t)N * 4);
    int* bsum      = (int*)take(4096 * 4);
    float* qb      = (float*)take(64 * 4);
    int* flag      = (int*)take(64);
    char* zbase    = ws + off;
    int* deg       = (int*)take((size_t)N * 4);          // zeroed
    long z4 = (long)(((ws + off) - zbase) / 16);

    int nblk = (N + 1023) / 1024;

    hipLaunchKernelGGL(k_detect, dim3(1), dim3(64), 0, stream, ei, flag);
    hipLaunchKernelGGL(k_zero, dim3((unsigned)((z4 + 255) / 256)), dim3(256), 0,
                       stream, (uint4*)zbase, z4);
    hipLaunchKernelGGL(k_q, dim3(1), dim3(64), 0, stream, We, ae, qb);
    hipLaunchKernelGGL(k_proj, dim3(N), dim3(128), 0, stream,
                       x, W, as_, ad_, xp, a_src, a_dst, N);
    hipLaunchKernelGGL(k_hist, dim3((E + 255) / 256), dim3(256), 0, stream,
                       ei, flag, deg, E);
    hipLaunchKernelGGL(k_scan1, dim3(nblk), dim3(256), 0, stream, deg, row, bsum, N);
    hipLaunchKernelGGL(k_scan2, dim3(1), dim3(64), 0, stream, bsum, nblk);
    hipLaunchKernelGGL(k_scan3, dim3((N + 255) / 256), dim3(256), 0, stream,
                       row, bsum, cursor, N, E);
    hipLaunchKernelGGL(k_place, dim3((E + 255) / 256), dim3(256), 0, stream,
                       ei, flag, ea, qb, a_src, cursor, srt_src, srt_val, E);
    hipLaunchKernelGGL(k_gather, dim3((N + 1) / 2), dim3(128), 0, stream,
                       row, srt_src, srt_val, a_dst, xp, bias, out, N);
}

// Round 4
// 372.390 us; speedup vs baseline: 2.9734x; 1.2341x over previous
//
#include <hip/hip_runtime.h>

// GATConv (PyG, edge_dim, concat): N=100000, E=1e6, IN=64, H=4, C=32.
// fp32 inputs: x[N,64], edge_index (int32/int64 auto-detected) [2,E],
// edge_attr[E,16], W[64,128], W_edge[16,128], att_src/dst/edge[4,32], bias[128].
// Output fp32 [N,128].
//
// Round 4: (a) register-tiled k_proj (64 nodes/block, 8x4 acc tile, W+x in LDS,
// wave-broadcast reads) replacing the L1-bound 1-node-per-block version;
// (b) xp stored as bf16 -> halves the gather's random-read bytes.

#define HC 128
#define NEG 0.2f
#define NEG_INF (-3.0e38f)

__device__ __forceinline__ float bf2f(unsigned short u) {
    return __uint_as_float(((unsigned)u) << 16);
}
__device__ __forceinline__ unsigned short f2bf(float f) {
    unsigned u = __float_as_uint(f);
    unsigned r = (u + 0x7fffu + ((u >> 16) & 1u)) >> 16;  // round-to-nearest-even
    return (unsigned short)r;
}

// edge_index may be int32 or raw int64 (LE, values < 2^31 => odd words zero).
__global__ void k_detect(const int* __restrict__ ei, int* __restrict__ flag) {
    if (threadIdx.x == 0) {
        int any = 0;
        for (int i = 1; i < 64; i += 2) any |= ei[i];
        flag[0] = (any == 0) ? 1 : 0;
    }
}
__device__ __forceinline__ long ld_idx(const int* __restrict__ ei, long i, int m64) {
    return m64 ? (long)(((const long long*)ei)[i]) : (long)ei[i];
}

__global__ void k_zero(uint4* __restrict__ p, long n4) {
    long i = (long)blockIdx.x * blockDim.x + threadIdx.x;
    if (i < n4) p[i] = make_uint4(0u, 0u, 0u, 0u);
}

// q[d*4+h] = sum_c W_edge[d, h*32+c] * att_edge[h, c]  (folds e_proj away)
__global__ void k_q(const float* __restrict__ We, const float* __restrict__ ae,
                    float* __restrict__ q) {
    int t = threadIdx.x;
    if (t >= 64) return;
    int d = t >> 2, h = t & 3;
    float s = 0.f;
    for (int c = 0; c < 32; ++c) s += We[d * HC + h * 32 + c] * ae[h * 32 + c];
    q[t] = s;
}

// 64 nodes x 128 cols per 256-thread block; thread tile = 8 nodes x 4 cols.
__global__ __launch_bounds__(256) void k_proj(
    const float* __restrict__ x, const float* __restrict__ W,
    const float* __restrict__ as_, const float* __restrict__ ad_,
    unsigned short* __restrict__ xp, float* __restrict__ a_src,
    float* __restrict__ a_dst, int N) {
    __shared__ float x_s[64][68];   // [k][node], stride 68 => 16B-aligned rows
    __shared__ float W_s[64][128];  // [k][col]
    int t = threadIdx.x;
    int n0 = blockIdx.x * 64;

    // stage W: 2048 float4, 8 per thread
#pragma unroll
    for (int i = 0; i < 8; ++i) {
        int fl = i * 256 + t;
        int k = fl >> 5, c4 = fl & 31;
        *reinterpret_cast<float4*>(&W_s[k][c4 * 4]) =
            *reinterpret_cast<const float4*>(&W[k * HC + c4 * 4]);
    }
    // stage x transposed: 1024 float4, 4 per thread
#pragma unroll
    for (int i = 0; i < 4; ++i) {
        int fl = i * 256 + t;
        int node = fl >> 4, f4 = fl & 15;
        float4 v = make_float4(0.f, 0.f, 0.f, 0.f);
        if (n0 + node < N)
            v = *reinterpret_cast<const float4*>(&x[(long)(n0 + node) * 64 + f4 * 4]);
        x_s[f4 * 4 + 0][node] = v.x;
        x_s[f4 * 4 + 1][node] = v.y;
        x_s[f4 * 4 + 2][node] = v.z;
        x_s[f4 * 4 + 3][node] = v.w;
    }
    __syncthreads();

    int c = t & 31;   // col group: cols c*4..c*4+3
    int nd = t >> 5;  // node group: nodes nd*8..nd*8+7
    float acc[8][4];
#pragma unroll
    for (int i = 0; i < 8; ++i)
#pragma unroll
        for (int j = 0; j < 4; ++j) acc[i][j] = 0.f;

    for (int k = 0; k < 64; ++k) {
        float4 w4 = *reinterpret_cast<const float4*>(&W_s[k][c * 4]);
        float4 xa = *reinterpret_cast<const float4*>(&x_s[k][nd * 8]);
        float4 xb = *reinterpret_cast<const float4*>(&x_s[k][nd * 8 + 4]);
        float xv[8] = {xa.x, xa.y, xa.z, xa.w, xb.x, xb.y, xb.z, xb.w};
#pragma unroll
        for (int i = 0; i < 8; ++i) {
            acc[i][0] += xv[i] * w4.x;
            acc[i][1] += xv[i] * w4.y;
            acc[i][2] += xv[i] * w4.z;
            acc[i][3] += xv[i] * w4.w;
        }
    }

    // store xp (bf16) + fused a_src/a_dst partials
    float4 s4 = *reinterpret_cast<const float4*>(&as_[c * 4]);
    float4 d4 = *reinterpret_cast<const float4*>(&ad_[c * 4]);
#pragma unroll
    for (int i = 0; i < 8; ++i) {
        int node = n0 + nd * 8 + i;
        if (node < N) {
            ushort4 o;
            o.x = f2bf(acc[i][0]); o.y = f2bf(acc[i][1]);
            o.z = f2bf(acc[i][2]); o.w = f2bf(acc[i][3]);
            *reinterpret_cast<ushort4*>(&xp[(long)node * HC + c * 4]) = o;
        }
        float ps = acc[i][0] * s4.x + acc[i][1] * s4.y + acc[i][2] * s4.z + acc[i][3] * s4.w;
        float pd = acc[i][0] * d4.x + acc[i][1] * d4.y + acc[i][2] * d4.z + acc[i][3] * d4.w;
#pragma unroll
        for (int off = 1; off < 8; off <<= 1) {
            ps += __shfl_xor(ps, off, 64);
            pd += __shfl_xor(pd, off, 64);
        }
        if ((c & 7) == 0 && node < N) {
            int h = c >> 3;
            a_src[(long)node * 4 + h] = ps;
            a_dst[(long)node * 4 + h] = pd;
        }
    }
}

// histogram of destinations
__global__ __launch_bounds__(256) void k_hist(
    const int* __restrict__ ei, const int* __restrict__ flag,
    int* __restrict__ deg, int E) {
    int e = blockIdx.x * blockDim.x + threadIdx.x;
    if (e >= E) return;
    long d = ld_idx(ei, (long)E + e, flag[0]);
    atomicAdd(&deg[d], 1);
}

// ---- exclusive scan over deg[N] (chunk=1024 per block of 256 threads) ----
__global__ __launch_bounds__(256) void k_scan1(
    const int* __restrict__ deg, int* __restrict__ row, int* __restrict__ bsum,
    int N) {
    __shared__ int s[256];
    int b = blockIdx.x, t = threadIdx.x;
    int base = b * 1024 + t * 4;
    int v[4], sum = 0;
#pragma unroll
    for (int i = 0; i < 4; ++i) {
        int idx = base + i;
        v[i] = (idx < N) ? deg[idx] : 0;
        sum += v[i];
    }
    s[t] = sum;
    __syncthreads();
    for (int off = 1; off < 256; off <<= 1) {
        int xv = (t >= off) ? s[t - off] : 0;
        __syncthreads();
        s[t] += xv;
        __syncthreads();
    }
    int run = s[t] - sum;
#pragma unroll
    for (int i = 0; i < 4; ++i) {
        int idx = base + i;
        if (idx < N) row[idx] = run;
        run += v[i];
    }
    if (t == 255) bsum[b] = s[255];
}

__global__ void k_scan2(int* __restrict__ bsum, int nb) {
    if (threadIdx.x == 0) {
        int run = 0;
        for (int i = 0; i < nb; ++i) { int v = bsum[i]; bsum[i] = run; run += v; }
    }
}

__global__ __launch_bounds__(256) void k_scan3(
    int* __restrict__ row, const int* __restrict__ bsum, int* __restrict__ cursor,
    int N, int E) {
    int i = blockIdx.x * blockDim.x + threadIdx.x;
    if (i < N) {
        int r = row[i] + bsum[i >> 10];
        row[i] = r;
        cursor[i] = r;
    }
    if (i == 0) row[N] = E;
}

// place edges into CSR order; precompute val[h] = a_src[src][h] + edge_attr.q
__global__ __launch_bounds__(256) void k_place(
    const int* __restrict__ ei, const int* __restrict__ flag,
    const float* __restrict__ ea, const float* __restrict__ q,
    const float* __restrict__ a_src, int* __restrict__ cursor,
    int* __restrict__ srt_src, float4* __restrict__ srt_val, int E) {
    int e = blockIdx.x * blockDim.x + threadIdx.x;
    if (e >= E) return;
    int m64 = flag[0];
    long s = ld_idx(ei, e, m64);
    long d = ld_idx(ei, (long)E + e, m64);
    const float4* pe = reinterpret_cast<const float4*>(ea + (long)e * 16);
    float4 e0 = pe[0], e1 = pe[1], e2 = pe[2], e3 = pe[3];
    float ev[16] = {e0.x, e0.y, e0.z, e0.w, e1.x, e1.y, e1.z, e1.w,
                    e2.x, e2.y, e2.z, e2.w, e3.x, e3.y, e3.z, e3.w};
    float4 s4 = *reinterpret_cast<const float4*>(a_src + s * 4);
    float sv[4] = {s4.x, s4.y, s4.z, s4.w};
    float ov[4];
#pragma unroll
    for (int h = 0; h < 4; ++h) {
        float aev = 0.f;
#pragma unroll
        for (int dd = 0; dd < 16; ++dd) aev += ev[dd] * q[dd * 4 + h];
        ov[h] = sv[h] + aev;
    }
    int pos = atomicAdd(&cursor[d], 1);
    srt_src[pos] = (int)s;
    srt_val[pos] = make_float4(ov[0], ov[1], ov[2], ov[3]);
}

// one wave (64 lanes) per destination node; 2 nodes per 128-block.
// online softmax; lane owns channels (lane, lane+64); xp is bf16.
__global__ __launch_bounds__(128) void k_gather(
    const int* __restrict__ row, const int* __restrict__ srt_src,
    const float4* __restrict__ srt_val, const float* __restrict__ a_dst,
    const unsigned short* __restrict__ xp, const float* __restrict__ bias,
    float* __restrict__ out, int N) {
    int wid = threadIdx.x >> 6;
    int lane = threadIdx.x & 63;
    int n = blockIdx.x * 2 + wid;
    if (n >= N) return;
    int beg = row[n], end = row[n + 1];
    float4 ad = *reinterpret_cast<const float4*>(a_dst + (long)n * 4);
    float adv[4] = {ad.x, ad.y, ad.z, ad.w};

    float m[4] = {NEG_INF, NEG_INF, NEG_INF, NEG_INF};
    float l[4] = {0.f, 0.f, 0.f, 0.f};
    float acc0 = 0.f, acc1 = 0.f;
    int h0 = lane >> 5, h1 = 2 + (lane >> 5);

    __shared__ float s_ex[2][64][4];
    __shared__ int s_src[2][64];

    for (int cs = beg; cs < end; cs += 64) {
        int cnt = min(64, end - cs);
        float a[4] = {NEG_INF, NEG_INF, NEG_INF, NEG_INF};
        int srcv = 0;
        if (lane < cnt) {
            srcv = srt_src[cs + lane];
            float4 v = srt_val[cs + lane];
            float t0 = v.x + adv[0], t1 = v.y + adv[1];
            float t2 = v.z + adv[2], t3 = v.w + adv[3];
            a[0] = (t0 > 0.f) ? t0 : NEG * t0;
            a[1] = (t1 > 0.f) ? t1 : NEG * t1;
            a[2] = (t2 > 0.f) ? t2 : NEG * t2;
            a[3] = (t3 > 0.f) ? t3 : NEG * t3;
        }
        float cm[4] = {a[0], a[1], a[2], a[3]};
#pragma unroll
        for (int off = 32; off > 0; off >>= 1) {
#pragma unroll
            for (int h = 0; h < 4; ++h)
                cm[h] = fmaxf(cm[h], __shfl_xor(cm[h], off, 64));
        }
        float nm[4], ex[4], sume[4];
#pragma unroll
        for (int h = 0; h < 4; ++h) {
            nm[h] = fmaxf(m[h], cm[h]);
            ex[h] = (lane < cnt) ? __expf(a[h] - nm[h]) : 0.f;
            sume[h] = ex[h];
        }
#pragma unroll
        for (int off = 32; off > 0; off >>= 1) {
#pragma unroll
            for (int h = 0; h < 4; ++h) sume[h] += __shfl_xor(sume[h], off, 64);
        }
        float sc[4];
#pragma unroll
        for (int h = 0; h < 4; ++h) {
            sc[h] = __expf(m[h] - nm[h]);
            l[h] = l[h] * sc[h] + sume[h];
            m[h] = nm[h];
        }
        acc0 *= sc[h0];
        acc1 *= sc[h1];
        s_src[wid][lane] = srcv;
#pragma unroll
        for (int h = 0; h < 4; ++h) s_ex[wid][lane][h] = ex[h];
        // single-wave lockstep: writes above precede reads below for all lanes
        for (int j = 0; j < cnt; ++j) {
            long s = s_src[wid][j];
            float w0 = s_ex[wid][j][h0];
            float w1 = s_ex[wid][j][h1];
            acc0 += w0 * bf2f(xp[s * HC + lane]);
            acc1 += w1 * bf2f(xp[s * HC + 64 + lane]);
        }
    }
    float d0 = l[h0] + 1e-16f, d1 = l[h1] + 1e-16f;
    out[(long)n * HC + lane] = acc0 / d0 + bias[lane];
    out[(long)n * HC + 64 + lane] = acc1 / d1 + bias[64 + lane];
}

extern "C" void kernel_launch(void* const* d_in, const int* in_sizes, int n_in,
                              void* d_out, int out_size, void* d_ws, size_t ws_size,
                              hipStream_t stream) {
    const float* x    = (const float*)d_in[0];
    const int*   ei   = (const int*)d_in[1];
    const float* ea   = (const float*)d_in[2];
    const float* W    = (const float*)d_in[3];
    const float* We   = (const float*)d_in[4];
    const float* as_  = (const float*)d_in[5];
    const float* ad_  = (const float*)d_in[6];
    const float* ae   = (const float*)d_in[7];
    const float* bias = (const float*)d_in[8];
    float* out = (float*)d_out;

    int N = in_sizes[0] / 64;
    int E = in_sizes[1] / 2;

    char* ws = (char*)d_ws;
    size_t off = 0;
    auto take = [&](size_t bytes) -> char* {
        char* p = ws + off;
        off += (bytes + 511) & ~(size_t)511;
        return p;
    };
    unsigned short* xp = (unsigned short*)take((size_t)N * HC * 2);  // 25.6 MB
    float* a_src   = (float*)take((size_t)N * 4 * 4);
    float* a_dst   = (float*)take((size_t)N * 4 * 4);
    float4* srt_val= (float4*)take((size_t)E * 16);                  // 16 MB
    int* srt_src   = (int*)take((size_t)E * 4);                      // 4 MB
    int* row       = (int*)take((size_t)(N + 1) * 4);
    int* cursor    = (int*)take((size_t)N * 4);
    int* bsum      = (int*)take(4096 * 4);
    float* qb      = (float*)take(64 * 4);
    int* flag      = (int*)take(64);
    char* zbase    = ws + off;
    int* deg       = (int*)take((size_t)N * 4);                      // zeroed
    long z4 = (long)(((ws + off) - zbase) / 16);

    int nblk = (N + 1023) / 1024;

    hipLaunchKernelGGL(k_detect, dim3(1), dim3(64), 0, stream, ei, flag);
    hipLaunchKernelGGL(k_zero, dim3((unsigned)((z4 + 255) / 256)), dim3(256), 0,
                       stream, (uint4*)zbase, z4);
    hipLaunchKernelGGL(k_q, dim3(1), dim3(64), 0, stream, We, ae, qb);
    hipLaunchKernelGGL(k_proj, dim3((N + 63) / 64), dim3(256), 0, stream,
                       x, W, as_, ad_, xp, a_src, a_dst, N);
    hipLaunchKernelGGL(k_hist, dim3((E + 255) / 256), dim3(256), 0, stream,
                       ei, flag, deg, E);
    hipLaunchKernelGGL(k_scan1, dim3(nblk), dim3(256), 0, stream, deg, row, bsum, N);
    hipLaunchKernelGGL(k_scan2, dim3(1), dim3(64), 0, stream, bsum, nblk);
    hipLaunchKernelGGL(k_scan3, dim3((N + 255) / 256), dim3(256), 0, stream,
                       row, bsum, cursor, N, E);
    hipLaunchKernelGGL(k_place, dim3((E + 255) / 256), dim3(256), 0, stream,
                       ei, flag, ea, qb, a_src, cursor, srt_src, srt_val, E);
    hipLaunchKernelGGL(k_gather, dim3((N + 1) / 2), dim3(128), 0, stream,
                       row, srt_src, srt_val, a_dst, xp, bias, out, N);
}

// Round 5
// 345.907 us; speedup vs baseline: 3.2010x; 1.0766x over previous
//
#include <hip/hip_runtime.h>

// GATConv (PyG, edge_dim, concat): N=100000, E=1e6, IN=64, H=4, C=32.
// fp32 inputs: x[N,64], edge_index (int32/int64 auto-detected) [2,E],
// edge_attr[E,16], W[64,128], W_edge[16,128], att_src/dst/edge[4,32], bias[128].
// Output fp32 [N,128].
//
// Round 5: (a) gather re-layout: softmax lanes = 16 edges x 4 heads (4-shfl
// reductions, chunk=16 ~ mean degree 10), channel lanes = 2 ch/lane w/ one
// dword bf16x2 load per edge; (b) serial k_detect/k_scan2 parallelized and
// zero+q+detect fused into k_init (8 launches total).

#define HC 128
#define NEG 0.2f
#define NEG_INF (-3.0e38f)
#define CH 16

__device__ __forceinline__ unsigned short f2bf(float f) {
    unsigned u = __float_as_uint(f);
    unsigned r = (u + 0x7fffu + ((u >> 16) & 1u)) >> 16;  // RNE
    return (unsigned short)r;
}

__device__ __forceinline__ long ld_idx(const int* __restrict__ ei, long i, int m64) {
    return m64 ? (long)(((const long long*)ei)[i]) : (long)ei[i];
}

// fused: zero deg region + q vector + int64-detect
__global__ __launch_bounds__(256) void k_init(
    uint4* __restrict__ zp, long z4, int zblocks,
    const float* __restrict__ We, const float* __restrict__ ae,
    float* __restrict__ q, const int* __restrict__ ei, int* __restrict__ flag) {
    int b = blockIdx.x, t = threadIdx.x;
    if (b < zblocks) {
        long i = (long)b * 256 + t;
        if (i < z4) zp[i] = make_uint4(0u, 0u, 0u, 0u);
    } else if (b == zblocks) {
        if (t < 64) {
            int d = t >> 2, h = t & 3;
            float s = 0.f;
            for (int c = 0; c < 32; ++c)
                s += We[d * HC + h * 32 + c] * ae[h * 32 + c];
            q[t] = s;
        }
    } else {
        // int64 LE with values < 2^31 => odd 32-bit words all zero
        if (t < 64) {
            int nz = (ei[2 * t + 1] != 0) ? 1 : 0;
            unsigned long long bal = __ballot(nz);
            if (t == 0) flag[0] = (bal == 0ull) ? 1 : 0;
        }
    }
}

// 64 nodes x 128 cols per 256-thread block; thread tile = 8 nodes x 4 cols.
__global__ __launch_bounds__(256) void k_proj(
    const float* __restrict__ x, const float* __restrict__ W,
    const float* __restrict__ as_, const float* __restrict__ ad_,
    unsigned short* __restrict__ xp, float* __restrict__ a_src,
    float* __restrict__ a_dst, int N) {
    __shared__ float x_s[64][68];
    __shared__ float W_s[64][128];
    int t = threadIdx.x;
    int n0 = blockIdx.x * 64;

#pragma unroll
    for (int i = 0; i < 8; ++i) {
        int fl = i * 256 + t;
        int k = fl >> 5, c4 = fl & 31;
        *reinterpret_cast<float4*>(&W_s[k][c4 * 4]) =
            *reinterpret_cast<const float4*>(&W[k * HC + c4 * 4]);
    }
#pragma unroll
    for (int i = 0; i < 4; ++i) {
        int fl = i * 256 + t;
        int node = fl >> 4, f4 = fl & 15;
        float4 v = make_float4(0.f, 0.f, 0.f, 0.f);
        if (n0 + node < N)
            v = *reinterpret_cast<const float4*>(&x[(long)(n0 + node) * 64 + f4 * 4]);
        x_s[f4 * 4 + 0][node] = v.x;
        x_s[f4 * 4 + 1][node] = v.y;
        x_s[f4 * 4 + 2][node] = v.z;
        x_s[f4 * 4 + 3][node] = v.w;
    }
    __syncthreads();

    int c = t & 31;
    int nd = t >> 5;
    float acc[8][4];
#pragma unroll
    for (int i = 0; i < 8; ++i)
#pragma unroll
        for (int j = 0; j < 4; ++j) acc[i][j] = 0.f;

    for (int k = 0; k < 64; ++k) {
        float4 w4 = *reinterpret_cast<const float4*>(&W_s[k][c * 4]);
        float4 xa = *reinterpret_cast<const float4*>(&x_s[k][nd * 8]);
        float4 xb = *reinterpret_cast<const float4*>(&x_s[k][nd * 8 + 4]);
        float xv[8] = {xa.x, xa.y, xa.z, xa.w, xb.x, xb.y, xb.z, xb.w};
#pragma unroll
        for (int i = 0; i < 8; ++i) {
            acc[i][0] += xv[i] * w4.x;
            acc[i][1] += xv[i] * w4.y;
            acc[i][2] += xv[i] * w4.z;
            acc[i][3] += xv[i] * w4.w;
        }
    }

    float4 s4 = *reinterpret_cast<const float4*>(&as_[c * 4]);
    float4 d4 = *reinterpret_cast<const float4*>(&ad_[c * 4]);
#pragma unroll
    for (int i = 0; i < 8; ++i) {
        int node = n0 + nd * 8 + i;
        if (node < N) {
            ushort4 o;
            o.x = f2bf(acc[i][0]); o.y = f2bf(acc[i][1]);
            o.z = f2bf(acc[i][2]); o.w = f2bf(acc[i][3]);
            *reinterpret_cast<ushort4*>(&xp[(long)node * HC + c * 4]) = o;
        }
        float ps = acc[i][0] * s4.x + acc[i][1] * s4.y + acc[i][2] * s4.z + acc[i][3] * s4.w;
        float pd = acc[i][0] * d4.x + acc[i][1] * d4.y + acc[i][2] * d4.z + acc[i][3] * d4.w;
#pragma unroll
        for (int off = 1; off < 8; off <<= 1) {
            ps += __shfl_xor(ps, off, 64);
            pd += __shfl_xor(pd, off, 64);
        }
        if ((c & 7) == 0 && node < N) {
            int h = c >> 3;
            a_src[(long)node * 4 + h] = ps;
            a_dst[(long)node * 4 + h] = pd;
        }
    }
}

__global__ __launch_bounds__(256) void k_hist(
    const int* __restrict__ ei, const int* __restrict__ flag,
    int* __restrict__ deg, int E) {
    int e = blockIdx.x * blockDim.x + threadIdx.x;
    if (e >= E) return;
    long d = ld_idx(ei, (long)E + e, flag[0]);
    atomicAdd(&deg[d], 1);
}

__global__ __launch_bounds__(256) void k_scan1(
    const int* __restrict__ deg, int* __restrict__ row, int* __restrict__ bsum,
    int N) {
    __shared__ int s[256];
    int b = blockIdx.x, t = threadIdx.x;
    int base = b * 1024 + t * 4;
    int v[4], sum = 0;
#pragma unroll
    for (int i = 0; i < 4; ++i) {
        int idx = base + i;
        v[i] = (idx < N) ? deg[idx] : 0;
        sum += v[i];
    }
    s[t] = sum;
    __syncthreads();
    for (int off = 1; off < 256; off <<= 1) {
        int xv = (t >= off) ? s[t - off] : 0;
        __syncthreads();
        s[t] += xv;
        __syncthreads();
    }
    int run = s[t] - sum;
#pragma unroll
    for (int i = 0; i < 4; ++i) {
        int idx = base + i;
        if (idx < N) row[idx] = run;
        run += v[i];
    }
    if (t == 255) bsum[b] = s[255];
}

// one-wave shfl scan over up to 128 block sums
__global__ void k_scan2(int* __restrict__ bsum, int nb) {
    int lane = threadIdx.x;
    if (lane >= 64) return;
    int i0 = 2 * lane, i1 = 2 * lane + 1;
    int v0 = (i0 < nb) ? bsum[i0] : 0;
    int v1 = (i1 < nb) ? bsum[i1] : 0;
    int s = v0 + v1;
#pragma unroll
    for (int off = 1; off < 64; off <<= 1) {
        int u = __shfl_up(s, off, 64);
        if (lane >= off) s += u;
    }
    int ex = s - (v0 + v1);
    if (i0 < nb) bsum[i0] = ex;
    if (i1 < nb) bsum[i1] = ex + v0;
}

__global__ __launch_bounds__(256) void k_scan3(
    int* __restrict__ row, const int* __restrict__ bsum, int* __restrict__ cursor,
    int N, int E) {
    int i = blockIdx.x * blockDim.x + threadIdx.x;
    if (i < N) {
        int r = row[i] + bsum[i >> 10];
        row[i] = r;
        cursor[i] = r;
    }
    if (i == 0) row[N] = E;
}

__global__ __launch_bounds__(256) void k_place(
    const int* __restrict__ ei, const int* __restrict__ flag,
    const float* __restrict__ ea, const float* __restrict__ q,
    const float* __restrict__ a_src, int* __restrict__ cursor,
    int* __restrict__ srt_src, float4* __restrict__ srt_val, int E) {
    int e = blockIdx.x * blockDim.x + threadIdx.x;
    if (e >= E) return;
    int m64 = flag[0];
    long s = ld_idx(ei, e, m64);
    long d = ld_idx(ei, (long)E + e, m64);
    const float4* pe = reinterpret_cast<const float4*>(ea + (long)e * 16);
    float4 e0 = pe[0], e1 = pe[1], e2 = pe[2], e3 = pe[3];
    float ev[16] = {e0.x, e0.y, e0.z, e0.w, e1.x, e1.y, e1.z, e1.w,
                    e2.x, e2.y, e2.z, e2.w, e3.x, e3.y, e3.z, e3.w};
    float4 s4 = *reinterpret_cast<const float4*>(a_src + s * 4);
    float sv[4] = {s4.x, s4.y, s4.z, s4.w};
    float ov[4];
#pragma unroll
    for (int h = 0; h < 4; ++h) {
        float aev = 0.f;
#pragma unroll
        for (int dd = 0; dd < 16; ++dd) aev += ev[dd] * q[dd * 4 + h];
        ov[h] = sv[h] + aev;
    }
    int pos = atomicAdd(&cursor[d], 1);
    srt_src[pos] = (int)s;
    srt_val[pos] = make_float4(ov[0], ov[1], ov[2], ov[3]);
}

// one wave per destination node; 2 nodes per 128-block.
// softmax phase: lane=(edge e=lane>>2, head h=lane&3), chunk=16 edges.
// channel phase: lane owns channels (2*lane, 2*lane+1), head = lane>>4.
__global__ __launch_bounds__(128) void k_gather(
    const int* __restrict__ row, const int* __restrict__ srt_src,
    const float* __restrict__ srt_valf, const float* __restrict__ a_dst,
    const char* __restrict__ xpc, const float* __restrict__ bias,
    float* __restrict__ out, int N) {
    int wid = threadIdx.x >> 6;
    int lane = threadIdx.x & 63;
    int n = blockIdx.x * 2 + wid;
    if (n >= N) return;
    int beg = row[n], end = row[n + 1];
    int h_s = lane & 3, e_s = lane >> 2;  // softmax role
    int h_a = lane >> 4;                  // channel-phase head
    float adv = a_dst[(long)n * 4 + h_s];
    float m = NEG_INF, l = 0.f;
    float acc0 = 0.f, acc1 = 0.f;

    __shared__ float s_ex[2][CH][4];
    __shared__ int s_off[2][CH];
    __shared__ float s_bc[2][8];  // [0..3]=sc, [4..7]=l

    for (int cs = beg; cs < end; cs += CH) {
        int cnt = end - cs;
        if (cnt > CH) cnt = CH;
        float a = NEG_INF;
        if (e_s < cnt) {
            float v = srt_valf[(long)(cs + e_s) * 4 + h_s] + adv;
            a = (v > 0.f) ? v : NEG * v;
        }
        if (h_s == 0 && e_s < cnt)
            s_off[wid][e_s] = srt_src[cs + e_s] << 8;  // byte offset of xp row
        float cm = a;
        cm = fmaxf(cm, __shfl_xor(cm, 4, 64));
        cm = fmaxf(cm, __shfl_xor(cm, 8, 64));
        cm = fmaxf(cm, __shfl_xor(cm, 16, 64));
        cm = fmaxf(cm, __shfl_xor(cm, 32, 64));
        float nm = fmaxf(m, cm);
        float ex = (e_s < cnt) ? __expf(a - nm) : 0.f;
        s_ex[wid][e_s][h_s] = ex;
        float se = ex;
        se += __shfl_xor(se, 4, 64);
        se += __shfl_xor(se, 8, 64);
        se += __shfl_xor(se, 16, 64);
        se += __shfl_xor(se, 32, 64);
        float sc = __expf(m - nm);
        l = l * sc + se;
        m = nm;
        if (lane < 4) s_bc[wid][h_s] = sc;  // lane<4 <=> e_s==0
        // single-wave lockstep: LDS writes above are program-ordered before
        // the reads below for all 64 lanes.
        float scl = s_bc[wid][h_a];
        acc0 *= scl;
        acc1 *= scl;
        for (int j = 0; j < cnt; ++j) {
            int off = s_off[wid][j];
            float w = s_ex[wid][j][h_a];
            unsigned v = *reinterpret_cast<const unsigned*>(xpc + off + lane * 4);
            acc0 += w * __uint_as_float(v << 16);
            acc1 += w * __uint_as_float(v & 0xffff0000u);
        }
    }
    if (lane < 4) s_bc[wid][4 + h_s] = l;
    float d = s_bc[wid][4 + h_a] + 1e-16f;
    float2 b2 = *reinterpret_cast<const float2*>(bias + lane * 2);
    float2 o;
    o.x = acc0 / d + b2.x;
    o.y = acc1 / d + b2.y;
    *reinterpret_cast<float2*>(out + (long)n * HC + lane * 2) = o;
}

extern "C" void kernel_launch(void* const* d_in, const int* in_sizes, int n_in,
                              void* d_out, int out_size, void* d_ws, size_t ws_size,
                              hipStream_t stream) {
    const float* x    = (const float*)d_in[0];
    const int*   ei   = (const int*)d_in[1];
    const float* ea   = (const float*)d_in[2];
    const float* W    = (const float*)d_in[3];
    const float* We   = (const float*)d_in[4];
    const float* as_  = (const float*)d_in[5];
    const float* ad_  = (const float*)d_in[6];
    const float* ae   = (const float*)d_in[7];
    const float* bias = (const float*)d_in[8];
    float* out = (float*)d_out;

    int N = in_sizes[0] / 64;
    int E = in_sizes[1] / 2;

    char* ws = (char*)d_ws;
    size_t off = 0;
    auto take = [&](size_t bytes) -> char* {
        char* p = ws + off;
        off += (bytes + 511) & ~(size_t)511;
        return p;
    };
    unsigned short* xp = (unsigned short*)take((size_t)N * HC * 2);  // 25.6 MB
    float* a_src   = (float*)take((size_t)N * 4 * 4);
    float* a_dst   = (float*)take((size_t)N * 4 * 4);
    float4* srt_val= (float4*)take((size_t)E * 16);                  // 16 MB
    int* srt_src   = (int*)take((size_t)E * 4);                      // 4 MB
    int* row       = (int*)take((size_t)(N + 1) * 4);
    int* cursor    = (int*)take((size_t)N * 4);
    int* bsum      = (int*)take(4096 * 4);
    float* qb      = (float*)take(64 * 4);
    int* flag      = (int*)take(64);
    char* zbase    = ws + off;
    int* deg       = (int*)take((size_t)N * 4);                      // zeroed
    long z4 = (long)(((ws + off) - zbase) / 16);

    int zblocks = (int)((z4 + 255) / 256);
    int nblk = (N + 1023) / 1024;

    hipLaunchKernelGGL(k_init, dim3(zblocks + 2), dim3(256), 0, stream,
                       (uint4*)zbase, z4, zblocks, We, ae, qb, ei, flag);
    hipLaunchKernelGGL(k_proj, dim3((N + 63) / 64), dim3(256), 0, stream,
                       x, W, as_, ad_, xp, a_src, a_dst, N);
    hipLaunchKernelGGL(k_hist, dim3((E + 255) / 256), dim3(256), 0, stream,
                       ei, flag, deg, E);
    hipLaunchKernelGGL(k_scan1, dim3(nblk), dim3(256), 0, stream, deg, row, bsum, N);
    hipLaunchKernelGGL(k_scan2, dim3(1), dim3(64), 0, stream, bsum, nblk);
    hipLaunchKernelGGL(k_scan3, dim3((N + 255) / 256), dim3(256), 0, stream,
                       row, bsum, cursor, N, E);
    hipLaunchKernelGGL(k_place, dim3((E + 255) / 256), dim3(256), 0, stream,
                       ei, flag, ea, qb, a_src, cursor, srt_src, srt_val, E);
    hipLaunchKernelGGL(k_gather, dim3((N + 1) / 2), dim3(128), 0, stream,
                       row, srt_src, (const float*)srt_val, a_dst,
                       (const char*)xp, bias, out, N);
}

// Round 7
// 313.944 us; speedup vs baseline: 3.5269x; 1.1018x over previous
//
#include <hip/hip_runtime.h>
#include <hip/hip_fp16.h>

// GATConv (PyG, edge_dim, concat): N=100000, E=1e6, IN=64, H=4, C=32.
// fp32 inputs: x[N,64], edge_index (int32/int64, per-block ballot detect) [2,E],
// edge_attr[E,16], W[64,128], W_edge[16,128], att_src/dst/edge[4,32], bias[128].
// Output fp32 [N,128].
//
// Round 6b: compile fix (cvt_pkrtz returns __fp16 ext-vector). Same plan:
// (a) gather channel-loop unrolled x4 (MLP); (b) 16B packed edge record
// {src, half4 full-logit}; (c) k_init gone (memset + per-block detect + q in
// k_scan2 wave 1).

#define HC 128
#define NEG 0.2f
#define NEG_INF (-3.0e38f)
#define CH 16

typedef __fp16 half2_t __attribute__((ext_vector_type(2)));

__device__ __forceinline__ unsigned short f2bf(float f) {
    unsigned u = __float_as_uint(f);
    return (unsigned short)((u + 0x7fffu + ((u >> 16) & 1u)) >> 16);  // RNE
}
__device__ __forceinline__ unsigned pk_h2(float lo, float hi) {
    half2_t p = __builtin_amdgcn_cvt_pkrtz(lo, hi);
    union { half2_t h; unsigned u; } cv;
    cv.h = p;
    return cv.u;
}
__device__ __forceinline__ float h2f_bits(unsigned short bits) {
    __half_raw hr; hr.x = bits;
    return __half2float(*reinterpret_cast<__half*>(&hr));
}
__device__ __forceinline__ long ld_idx(const int* __restrict__ ei, long i, int m64) {
    return m64 ? (long)(((const long long*)ei)[i]) : (long)ei[i];
}
// per-block int64 detect: int64 LE with values < 2^31 => odd 32-bit words zero.
// Must be called with >=64 threads, before any divergent return.
__device__ __forceinline__ int detect_m64(const int* __restrict__ ei, int* s_m64) {
    int t = threadIdx.x;
    if (t < 64) {
        unsigned long long bal = __ballot(ei[2 * t + 1] != 0);
        if (t == 0) *s_m64 = (bal == 0ull) ? 1 : 0;
    }
    __syncthreads();
    return *s_m64;
}

// 64 nodes x 128 cols per 256-thread block; thread tile = 8 nodes x 4 cols.
__global__ __launch_bounds__(256) void k_proj(
    const float* __restrict__ x, const float* __restrict__ W,
    const float* __restrict__ as_, const float* __restrict__ ad_,
    unsigned short* __restrict__ xp, float* __restrict__ a_src,
    float* __restrict__ a_dst, int N) {
    __shared__ float x_s[64][68];
    __shared__ float W_s[64][128];
    int t = threadIdx.x;
    int n0 = blockIdx.x * 64;

#pragma unroll
    for (int i = 0; i < 8; ++i) {
        int fl = i * 256 + t;
        int k = fl >> 5, c4 = fl & 31;
        *reinterpret_cast<float4*>(&W_s[k][c4 * 4]) =
            *reinterpret_cast<const float4*>(&W[k * HC + c4 * 4]);
    }
#pragma unroll
    for (int i = 0; i < 4; ++i) {
        int fl = i * 256 + t;
        int node = fl >> 4, f4 = fl & 15;
        float4 v = make_float4(0.f, 0.f, 0.f, 0.f);
        if (n0 + node < N)
            v = *reinterpret_cast<const float4*>(&x[(long)(n0 + node) * 64 + f4 * 4]);
        x_s[f4 * 4 + 0][node] = v.x;
        x_s[f4 * 4 + 1][node] = v.y;
        x_s[f4 * 4 + 2][node] = v.z;
        x_s[f4 * 4 + 3][node] = v.w;
    }
    __syncthreads();

    int c = t & 31;
    int nd = t >> 5;
    float acc[8][4];
#pragma unroll
    for (int i = 0; i < 8; ++i)
#pragma unroll
        for (int j = 0; j < 4; ++j) acc[i][j] = 0.f;

    for (int k = 0; k < 64; ++k) {
        float4 w4 = *reinterpret_cast<const float4*>(&W_s[k][c * 4]);
        float4 xa = *reinterpret_cast<const float4*>(&x_s[k][nd * 8]);
        float4 xb = *reinterpret_cast<const float4*>(&x_s[k][nd * 8 + 4]);
        float xv[8] = {xa.x, xa.y, xa.z, xa.w, xb.x, xb.y, xb.z, xb.w};
#pragma unroll
        for (int i = 0; i < 8; ++i) {
            acc[i][0] += xv[i] * w4.x;
            acc[i][1] += xv[i] * w4.y;
            acc[i][2] += xv[i] * w4.z;
            acc[i][3] += xv[i] * w4.w;
        }
    }

    float4 s4 = *reinterpret_cast<const float4*>(&as_[c * 4]);
    float4 d4 = *reinterpret_cast<const float4*>(&ad_[c * 4]);
#pragma unroll
    for (int i = 0; i < 8; ++i) {
        int node = n0 + nd * 8 + i;
        if (node < N) {
            ushort4 o;
            o.x = f2bf(acc[i][0]); o.y = f2bf(acc[i][1]);
            o.z = f2bf(acc[i][2]); o.w = f2bf(acc[i][3]);
            *reinterpret_cast<ushort4*>(&xp[(long)node * HC + c * 4]) = o;
        }
        float ps = acc[i][0] * s4.x + acc[i][1] * s4.y + acc[i][2] * s4.z + acc[i][3] * s4.w;
        float pd = acc[i][0] * d4.x + acc[i][1] * d4.y + acc[i][2] * d4.z + acc[i][3] * d4.w;
#pragma unroll
        for (int off = 1; off < 8; off <<= 1) {
            ps += __shfl_xor(ps, off, 64);
            pd += __shfl_xor(pd, off, 64);
        }
        if ((c & 7) == 0 && node < N) {
            int h = c >> 3;
            a_src[(long)node * 4 + h] = ps;
            a_dst[(long)node * 4 + h] = pd;
        }
    }
}

__global__ __launch_bounds__(256) void k_hist(
    const int* __restrict__ ei, int* __restrict__ deg, int E) {
    __shared__ int s_m64;
    int m64 = detect_m64(ei, &s_m64);
    int e = blockIdx.x * blockDim.x + threadIdx.x;
    if (e >= E) return;
    long d = ld_idx(ei, (long)E + e, m64);
    atomicAdd(&deg[d], 1);
}

__global__ __launch_bounds__(256) void k_scan1(
    const int* __restrict__ deg, int* __restrict__ row, int* __restrict__ bsum,
    int N) {
    __shared__ int s[256];
    int b = blockIdx.x, t = threadIdx.x;
    int base = b * 1024 + t * 4;
    int v[4], sum = 0;
#pragma unroll
    for (int i = 0; i < 4; ++i) {
        int idx = base + i;
        v[i] = (idx < N) ? deg[idx] : 0;
        sum += v[i];
    }
    s[t] = sum;
    __syncthreads();
    for (int off = 1; off < 256; off <<= 1) {
        int xv = (t >= off) ? s[t - off] : 0;
        __syncthreads();
        s[t] += xv;
        __syncthreads();
    }
    int run = s[t] - sum;
#pragma unroll
    for (int i = 0; i < 4; ++i) {
        int idx = base + i;
        if (idx < N) row[idx] = run;
        run += v[i];
    }
    if (t == 255) bsum[b] = s[255];
}

// wave 0: shfl scan over up to 128 block sums; wave 1: q[64] precompute.
__global__ void k_scan2(int* __restrict__ bsum, int nb,
                        const float* __restrict__ We, const float* __restrict__ ae,
                        float* __restrict__ q) {
    int t = threadIdx.x;
    if (t < 64) {
        int i0 = 2 * t, i1 = 2 * t + 1;
        int v0 = (i0 < nb) ? bsum[i0] : 0;
        int v1 = (i1 < nb) ? bsum[i1] : 0;
        int s = v0 + v1;
#pragma unroll
        for (int off = 1; off < 64; off <<= 1) {
            int u = __shfl_up(s, off, 64);
            if (t >= off) s += u;
        }
        int ex = s - (v0 + v1);
        if (i0 < nb) bsum[i0] = ex;
        if (i1 < nb) bsum[i1] = ex + v0;
    } else {
        int tt = t - 64;
        int d = tt >> 2, h = tt & 3;
        float s = 0.f;
        for (int c = 0; c < 32; ++c)
            s += We[d * HC + h * 32 + c] * ae[h * 32 + c];
        q[tt] = s;
    }
}

__global__ __launch_bounds__(256) void k_scan3(
    int* __restrict__ row, const int* __restrict__ bsum, int* __restrict__ cursor,
    int N, int E) {
    int i = blockIdx.x * blockDim.x + threadIdx.x;
    if (i < N) {
        int r = row[i] + bsum[i >> 10];
        row[i] = r;
        cursor[i] = r;
    }
    if (i == 0) row[N] = E;
}

// per edge: full logit = leaky(a_src[s] + a_dst[d] + ea.q), fp16x4-packed with
// src into ONE 16B record at CSR position.
__global__ __launch_bounds__(256) void k_place(
    const int* __restrict__ ei, const float* __restrict__ ea,
    const float* __restrict__ q, const float* __restrict__ a_src,
    const float* __restrict__ a_dst, int* __restrict__ cursor,
    uint4* __restrict__ srt, int E) {
    __shared__ int s_m64;
    int m64 = detect_m64(ei, &s_m64);
    int e = blockIdx.x * blockDim.x + threadIdx.x;
    if (e >= E) return;
    long s = ld_idx(ei, e, m64);
    long d = ld_idx(ei, (long)E + e, m64);
    const float4* pe = reinterpret_cast<const float4*>(ea + (long)e * 16);
    float4 e0 = pe[0], e1 = pe[1], e2 = pe[2], e3 = pe[3];
    float ev[16] = {e0.x, e0.y, e0.z, e0.w, e1.x, e1.y, e1.z, e1.w,
                    e2.x, e2.y, e2.z, e2.w, e3.x, e3.y, e3.z, e3.w};
    float4 s4 = *reinterpret_cast<const float4*>(a_src + s * 4);
    float4 d4 = *reinterpret_cast<const float4*>(a_dst + d * 4);
    float sv[4] = {s4.x + d4.x, s4.y + d4.y, s4.z + d4.z, s4.w + d4.w};
    float ov[4];
#pragma unroll
    for (int h = 0; h < 4; ++h) {
        float aev = 0.f;
#pragma unroll
        for (int dd = 0; dd < 16; ++dd) aev += ev[dd] * q[dd * 4 + h];
        float al = sv[h] + aev;
        ov[h] = (al > 0.f) ? al : NEG * al;
    }
    int pos = atomicAdd(&cursor[d], 1);
    srt[pos] = make_uint4((unsigned)s, pk_h2(ov[0], ov[1]), pk_h2(ov[2], ov[3]), 0u);
}

// one wave per destination node; 2 nodes per 128-block.
// softmax phase: lane=(edge e=lane>>2, head h=lane&3), chunk=16 edges.
// channel phase: lane owns channels (2*lane, 2*lane+1), head = lane>>4;
// j-loop unrolled x4 for memory-level parallelism.
__global__ __launch_bounds__(128) void k_gather(
    const int* __restrict__ row, const uint4* __restrict__ srt,
    const char* __restrict__ xpc, const float* __restrict__ bias,
    float* __restrict__ out, int N) {
    int wid = threadIdx.x >> 6;
    int lane = threadIdx.x & 63;
    int n = blockIdx.x * 2 + wid;
    if (n >= N) return;
    int beg = row[n], end = row[n + 1];
    int h_s = lane & 3, e_s = lane >> 2;  // softmax role
    int h_a = lane >> 4;                  // channel-phase head
    float m = NEG_INF, l = 0.f;
    float acc0 = 0.f, acc1 = 0.f;

    __shared__ float s_ex[2][CH][4];
    __shared__ int s_off[2][CH];
    __shared__ float s_bc[2][8];  // [0..3]=sc, [4..7]=l

    for (int cs = beg; cs < end; cs += CH) {
        int cnt = end - cs;
        if (cnt > CH) cnt = CH;
        float a = NEG_INF;
        if (e_s < cnt) {
            uint4 r = srt[cs + e_s];
            if (h_s == 0) s_off[wid][e_s] = (int)(r.x << 8);  // xp row byte off
            unsigned pr = (h_s & 2) ? r.z : r.y;
            unsigned bits = (h_s & 1) ? (pr >> 16) : (pr & 0xffffu);
            a = h2f_bits((unsigned short)bits);
        }
        float cm = a;
        cm = fmaxf(cm, __shfl_xor(cm, 4, 64));
        cm = fmaxf(cm, __shfl_xor(cm, 8, 64));
        cm = fmaxf(cm, __shfl_xor(cm, 16, 64));
        cm = fmaxf(cm, __shfl_xor(cm, 32, 64));
        float nm = fmaxf(m, cm);
        float ex = (e_s < cnt) ? __expf(a - nm) : 0.f;
        s_ex[wid][e_s][h_s] = ex;
        float se = ex;
        se += __shfl_xor(se, 4, 64);
        se += __shfl_xor(se, 8, 64);
        se += __shfl_xor(se, 16, 64);
        se += __shfl_xor(se, 32, 64);
        float sc = __expf(m - nm);
        l = l * sc + se;
        m = nm;
        if (lane < 4) s_bc[wid][h_s] = sc;  // lane<4 <=> e_s==0
        // single-wave lockstep: LDS writes above are program-ordered before
        // the reads below for all 64 lanes.
        float scl = s_bc[wid][h_a];
        acc0 *= scl;
        acc1 *= scl;
        int j = 0;
        for (; j + 4 <= cnt; j += 4) {
            int o0 = s_off[wid][j + 0], o1 = s_off[wid][j + 1];
            int o2 = s_off[wid][j + 2], o3 = s_off[wid][j + 3];
            float w0 = s_ex[wid][j + 0][h_a], w1 = s_ex[wid][j + 1][h_a];
            float w2 = s_ex[wid][j + 2][h_a], w3 = s_ex[wid][j + 3][h_a];
            unsigned v0 = *reinterpret_cast<const unsigned*>(xpc + o0 + lane * 4);
            unsigned v1 = *reinterpret_cast<const unsigned*>(xpc + o1 + lane * 4);
            unsigned v2 = *reinterpret_cast<const unsigned*>(xpc + o2 + lane * 4);
            unsigned v3 = *reinterpret_cast<const unsigned*>(xpc + o3 + lane * 4);
            acc0 += w0 * __uint_as_float(v0 << 16);
            acc1 += w0 * __uint_as_float(v0 & 0xffff0000u);
            acc0 += w1 * __uint_as_float(v1 << 16);
            acc1 += w1 * __uint_as_float(v1 & 0xffff0000u);
            acc0 += w2 * __uint_as_float(v2 << 16);
            acc1 += w2 * __uint_as_float(v2 & 0xffff0000u);
            acc0 += w3 * __uint_as_float(v3 << 16);
            acc1 += w3 * __uint_as_float(v3 & 0xffff0000u);
        }
        for (; j < cnt; ++j) {
            int o = s_off[wid][j];
            float w = s_ex[wid][j][h_a];
            unsigned v = *reinterpret_cast<const unsigned*>(xpc + o + lane * 4);
            acc0 += w * __uint_as_float(v << 16);
            acc1 += w * __uint_as_float(v & 0xffff0000u);
        }
    }
    if (lane < 4) s_bc[wid][4 + h_s] = l;
    float d = s_bc[wid][4 + h_a] + 1e-16f;
    float2 b2 = *reinterpret_cast<const float2*>(bias + lane * 2);
    float2 o;
    o.x = acc0 / d + b2.x;
    o.y = acc1 / d + b2.y;
    *reinterpret_cast<float2*>(out + (long)n * HC + lane * 2) = o;
}

extern "C" void kernel_launch(void* const* d_in, const int* in_sizes, int n_in,
                              void* d_out, int out_size, void* d_ws, size_t ws_size,
                              hipStream_t stream) {
    const float* x    = (const float*)d_in[0];
    const int*   ei   = (const int*)d_in[1];
    const float* ea   = (const float*)d_in[2];
    const float* W    = (const float*)d_in[3];
    const float* We   = (const float*)d_in[4];
    const float* as_  = (const float*)d_in[5];
    const float* ad_  = (const float*)d_in[6];
    const float* ae   = (const float*)d_in[7];
    const float* bias = (const float*)d_in[8];
    float* out = (float*)d_out;

    int N = in_sizes[0] / 64;
    int E = in_sizes[1] / 2;

    char* ws = (char*)d_ws;
    size_t off = 0;
    auto take = [&](size_t bytes) -> char* {
        char* p = ws + off;
        off += (bytes + 511) & ~(size_t)511;
        return p;
    };
    unsigned short* xp = (unsigned short*)take((size_t)N * HC * 2);  // 25.6 MB
    float* a_src   = (float*)take((size_t)N * 4 * 4);
    float* a_dst   = (float*)take((size_t)N * 4 * 4);
    uint4* srt     = (uint4*)take((size_t)E * 16);                   // 16 MB
    int* row       = (int*)take((size_t)(N + 1) * 4);
    int* cursor    = (int*)take((size_t)N * 4);
    int* bsum      = (int*)take(4096 * 4);
    float* qb      = (float*)take(64 * 4);
    int* deg       = (int*)take((size_t)N * 4);

    int nblk = (N + 1023) / 1024;

    (void)hipMemsetAsync(deg, 0, (size_t)N * 4, stream);
    hipLaunchKernelGGL(k_proj, dim3((N + 63) / 64), dim3(256), 0, stream,
                       x, W, as_, ad_, xp, a_src, a_dst, N);
    hipLaunchKernelGGL(k_hist, dim3((E + 255) / 256), dim3(256), 0, stream,
                       ei, deg, E);
    hipLaunchKernelGGL(k_scan1, dim3(nblk), dim3(256), 0, stream, deg, row, bsum, N);
    hipLaunchKernelGGL(k_scan2, dim3(1), dim3(128), 0, stream, bsum, nblk, We, ae, qb);
    hipLaunchKernelGGL(k_scan3, dim3((N + 255) / 256), dim3(256), 0, stream,
                       row, bsum, cursor, N, E);
    hipLaunchKernelGGL(k_place, dim3((E + 255) / 256), dim3(256), 0, stream,
                       ei, ea, qb, a_src, a_dst, cursor, srt, E);
    hipLaunchKernelGGL(k_gather, dim3((N + 1) / 2), dim3(128), 0, stream,
                       row, srt, (const char*)xp, bias, out, N);
}